// Round 5
// baseline (418.127 us; speedup 1.0000x reference)
//
#include <hip/hip_runtime.h>
#include <stdint.h>
#include <stddef.h>

// GraphSAGE-mean 2-layer pipeline on MI355X — round 5.
//   h   = relu(feat @ W_init + b_init)                      [200000,128] bf16 (ws)
//   l0: hn = segment_mean(h[src0], dst0); h1 = relu(h[:50000]@Ws + hn@Wn + b)  bf16
//   l1: hn = segment_mean(h1[src1], dst1); out = h1[:10000]@Ws + hn@Wn + b    f32
//
// R5 changes vs R4 (accounting: agg+sage chain ~190 us never profiled; 7 nodes
// of dispatch gaps):
//  - agg+sage FUSED per layer: block gathers 16 dst rows' means into an LDS
//    tile (padded rows, 2-way-free banks), barrier, then 4 waves do the
//    16-row dual GEMM (2 nt cols/wave) from LDS hn + global hself. hn buffer
//    and 2 dispatches eliminated.
//  - prep_w kernel eliminated: every GEMM kernel self-builds its W fragments
//    in LDS from raw f32 W (coalesced read, L3-resident, one-time per block).
//  - pipeline: memset(cnt) -> place -> fc_init -> sage0_fused -> sage1_fused.

#define DIM 128
constexpr int N_SRC0 = 200000;
constexpr int N_DST0 = 50000;
constexpr int N_DST1 = 10000;
constexpr int E0 = 800000;
constexpr int E1 = 160000;
constexpr int MAXDEG = 64;   // Poisson(16): max deg over 50k bins ~45 — safe
constexpr int HNP = 136;     // hn LDS row pitch in shorts (272 B: 16B-aligned,
                             // 68 words -> lanes step 4 banks, 2-way = free)

typedef __attribute__((ext_vector_type(8))) short bf16x8;   // 8 bf16 = 4 VGPRs
typedef __attribute__((ext_vector_type(4))) float f32x4;    // MFMA C/D

__device__ __forceinline__ uint16_t f2bf(float f) {
  union { float f; uint32_t u; } v; v.f = f;
  return (uint16_t)((v.u + 0x7FFFu + ((v.u >> 16) & 1u)) >> 16);  // RNE
}
__device__ __forceinline__ float bf2f(uint16_t h) {
  union { uint32_t u; float f; } v; v.u = ((uint32_t)h) << 16;
  return v.f;
}

// Fill a 16384-short LDS region with W (f32, [128][128]) in MFMA-frag order:
// frag[((kc*8+nt)*64 + lane)*8 + j] = bf16(W[kc*32 + (lane>>4)*8 + j][nt*16 + (lane&15)])
// Reads W coalesced (i contiguous); scattered 2B LDS writes (one-time cost).
__device__ __forceinline__ void build_w_frags(const float* __restrict__ W,
                                              uint16_t* __restrict__ frag) {
  for (int i = threadIdx.x; i < 16384; i += 256) {
    int k = i >> 7, n = i & 127;
    int kc = k >> 5, q = (k >> 3) & 3, j = k & 7;
    int nt = n >> 4, ll = n & 15;
    frag[((kc * 8 + nt) * 64 + q * 16 + ll) * 8 + j] = f2bf(W[i]);
  }
}

// ---------------------------------------------------------------------------
// place: dst-partitioned slot-scatter (partition = blockIdx&7, XCD heuristic).
// ---------------------------------------------------------------------------
__global__ __launch_bounds__(256) void place_kernel(
    const int* __restrict__ src0, const int* __restrict__ dst0,
    const int* __restrict__ src1, const int* __restrict__ dst1,
    int* __restrict__ cnt0, int* __restrict__ cnt1,
    int* __restrict__ eslot0, int* __restrict__ eslot1) {
  int part = blockIdx.x & 7;
  int bpp  = gridDim.x >> 3;
  int bidx = blockIdx.x >> 3;
  const int4* s04 = (const int4*)src0;
  const int4* d04 = (const int4*)dst0;
  const int4* s14 = (const int4*)src1;
  const int4* d14 = (const int4*)dst1;

  int lo = part * (N_DST0 / 8), hi = lo + (N_DST0 / 8);
  for (int i = bidx * 256 + threadIdx.x; i < E0 / 4; i += bpp * 256) {
    int4 d = d04[i]; int4 s = s04[i];
    if (d.x >= lo && d.x < hi) { int p = atomicAdd(&cnt0[d.x], 1); if (p < MAXDEG) eslot0[(size_t)d.x * MAXDEG + p] = s.x; }
    if (d.y >= lo && d.y < hi) { int p = atomicAdd(&cnt0[d.y], 1); if (p < MAXDEG) eslot0[(size_t)d.y * MAXDEG + p] = s.y; }
    if (d.z >= lo && d.z < hi) { int p = atomicAdd(&cnt0[d.z], 1); if (p < MAXDEG) eslot0[(size_t)d.z * MAXDEG + p] = s.z; }
    if (d.w >= lo && d.w < hi) { int p = atomicAdd(&cnt0[d.w], 1); if (p < MAXDEG) eslot0[(size_t)d.w * MAXDEG + p] = s.w; }
  }
  int lo1 = part * (N_DST1 / 8), hi1 = lo1 + (N_DST1 / 8);
  for (int i = bidx * 256 + threadIdx.x; i < E1 / 4; i += bpp * 256) {
    int4 d = d14[i]; int4 s = s14[i];
    if (d.x >= lo1 && d.x < hi1) { int p = atomicAdd(&cnt1[d.x], 1); if (p < MAXDEG) eslot1[(size_t)d.x * MAXDEG + p] = s.x; }
    if (d.y >= lo1 && d.y < hi1) { int p = atomicAdd(&cnt1[d.y], 1); if (p < MAXDEG) eslot1[(size_t)d.y * MAXDEG + p] = s.y; }
    if (d.z >= lo1 && d.z < hi1) { int p = atomicAdd(&cnt1[d.z], 1); if (p < MAXDEG) eslot1[(size_t)d.z * MAXDEG + p] = s.z; }
    if (d.w >= lo1 && d.w < hi1) { int p = atomicAdd(&cnt1[d.w], 1); if (p < MAXDEG) eslot1[(size_t)d.w * MAXDEG + p] = s.w; }
  }
}

// ---------------------------------------------------------------------------
// fc_init: h = relu(feat @ W + b). 32-row feat tiles double-buffered via
// global_load_lds width=16; self-built W frags in LDS. 64 KB -> 2 blocks/CU.
// ---------------------------------------------------------------------------
__global__ __launch_bounds__(256) void fc_init_kernel(
    const float* __restrict__ feat, const float* __restrict__ W,
    const float* __restrict__ bias, uint16_t* __restrict__ hout) {
  __shared__ uint16_t wl[16384];                  // 32 KB W fragments
  __shared__ __align__(16) float tile[2][4096];   // 2 x 32 rows x 128 cols f32
  build_w_frags(W, wl);

  const int tid = threadIdx.x;
  const int w = tid >> 6, lane = tid & 63;
  const int q = lane >> 4, m16 = lane & 15;
  const int sl = w >> 1, nh = w & 1;   // strip-in-tile, nt-half

  float bv[4];
#pragma unroll
  for (int j = 0; j < 4; j++) bv[j] = bias[(nh * 4 + j) * 16 + m16];

  const int ntiles = N_SRC0 / 32;   // 6250
  const int stride = gridDim.x;

  auto stage = [&](int t, int buf) {
    const float* gbase = feat + (size_t)t * 4096 + w * 1024 + lane * 4;
    float* lbase = &tile[buf][w * 1024];
#pragma unroll
    for (int i = 0; i < 4; i++) {
      __builtin_amdgcn_global_load_lds(
          (const __attribute__((address_space(1))) uint32_t*)(gbase + i * 256),
          (__attribute__((address_space(3))) uint32_t*)(lbase + i * 256),
          16, 0, 0);
    }
  };

  int t = blockIdx.x;
  int cur = 0;
  if (t < ntiles) stage(t, 0);
  __syncthreads();

  while (t < ntiles) {
    int tn = t + stride;
    if (tn < ntiles) stage(tn, cur ^ 1);

    f32x4 acc[4];
#pragma unroll
    for (int j = 0; j < 4; j++) acc[j] = (f32x4){0.f, 0.f, 0.f, 0.f};

    const float* arow = &tile[cur][(sl * 16 + m16) * 128];
#pragma unroll
    for (int kc = 0; kc < 4; kc++) {
      float4 x0 = *(const float4*)(arow + kc * 32 + q * 8);
      float4 x1 = *(const float4*)(arow + kc * 32 + q * 8 + 4);
      float xs[8] = {x0.x, x0.y, x0.z, x0.w, x1.x, x1.y, x1.z, x1.w};
      bf16x8 a;
#pragma unroll
      for (int j = 0; j < 8; j++) a[j] = (short)f2bf(xs[j]);
#pragma unroll
      for (int j = 0; j < 4; j++) {
        int nt = nh * 4 + j;
        bf16x8 wv = *(const bf16x8*)&wl[((kc * 8 + nt) * 64 + lane) * 8];
        acc[j] = __builtin_amdgcn_mfma_f32_16x16x32_bf16(a, wv, acc[j], 0, 0, 0);
      }
    }

    int rowb = t * 32 + sl * 16 + q * 4;
#pragma unroll
    for (int j = 0; j < 4; j++)
#pragma unroll
      for (int r = 0; r < 4; r++) {
        float v = fmaxf(acc[j][r] + bv[j], 0.f);
        hout[(size_t)(rowb + r) * DIM + (nh * 4 + j) * 16 + m16] = f2bf(v);
      }

    __syncthreads();
    cur ^= 1;
    t = tn;
  }
}

// ---------------------------------------------------------------------------
// sage_fused: per 16-dst group — gather means into LDS hn tile, then dual GEMM
//   out = act(hself@Ws + hn@Wn + bS + bN)
// Gather: wave w owns rows w*4..w*4+3, lane owns 2 cols, 8 loads in flight.
// GEMM: wave w owns nt {2w, 2w+1}; aS from global, aN from LDS hn.
// LDS: 32+32 KB W frags + 4.25 KB hn = 68.3 KB -> 2 blocks/CU.
// ---------------------------------------------------------------------------
template <bool ACT, bool OUT_BF16>
__global__ __launch_bounds__(256) void sage_fused_kernel(
    const int* __restrict__ eslot, const int* __restrict__ deg,
    const uint16_t* __restrict__ hsrc, const uint16_t* __restrict__ hself,
    const float* __restrict__ WS, const float* __restrict__ WN,
    const float* __restrict__ bS, const float* __restrict__ bN,
    void* __restrict__ outp, int n_dst) {
  __shared__ uint16_t wS[16384];
  __shared__ uint16_t wN[16384];
  __shared__ uint16_t hn[16 * HNP];
  build_w_frags(WS, wS);
  build_w_frags(WN, wN);
  __syncthreads();

  const int w = threadIdx.x >> 6, lane = threadIdx.x & 63;
  const int q = lane >> 4, m16 = lane & 15;

  float bv[2];
#pragma unroll
  for (int j = 0; j < 2; j++) {
    int nt = w * 2 + j;
    bv[j] = bS[nt * 16 + m16] + bN[nt * 16 + m16];
  }

  const int ngroups = n_dst / 16;
  for (int g = blockIdx.x; g < ngroups; g += gridDim.x) {
    int m0 = g * 16;

    // ---- gather phase: mean of h[src] rows into hn tile ----
#pragma unroll
    for (int rr = 0; rr < 4; rr++) {
      int d = m0 + w * 4 + rr;
      const int* sl = eslot + (size_t)d * MAXDEG;
      int dg = deg[d];
      int dgc = dg < MAXDEG ? dg : MAXDEG;
      float a0 = 0.f, a1 = 0.f;
      int e = 0;
      for (; e + 8 <= dgc; e += 8) {
        int4 sa = *(const int4*)(sl + e);
        int4 sb = *(const int4*)(sl + e + 4);
        uint32_t p0 = *(const uint32_t*)(hsrc + (size_t)sa.x * DIM + lane * 2);
        uint32_t p1 = *(const uint32_t*)(hsrc + (size_t)sa.y * DIM + lane * 2);
        uint32_t p2 = *(const uint32_t*)(hsrc + (size_t)sa.z * DIM + lane * 2);
        uint32_t p3 = *(const uint32_t*)(hsrc + (size_t)sa.w * DIM + lane * 2);
        uint32_t p4 = *(const uint32_t*)(hsrc + (size_t)sb.x * DIM + lane * 2);
        uint32_t p5 = *(const uint32_t*)(hsrc + (size_t)sb.y * DIM + lane * 2);
        uint32_t p6 = *(const uint32_t*)(hsrc + (size_t)sb.z * DIM + lane * 2);
        uint32_t p7 = *(const uint32_t*)(hsrc + (size_t)sb.w * DIM + lane * 2);
        a0 += bf2f((uint16_t)p0) + bf2f((uint16_t)p1) + bf2f((uint16_t)p2) + bf2f((uint16_t)p3)
            + bf2f((uint16_t)p4) + bf2f((uint16_t)p5) + bf2f((uint16_t)p6) + bf2f((uint16_t)p7);
        a1 += bf2f((uint16_t)(p0 >> 16)) + bf2f((uint16_t)(p1 >> 16)) + bf2f((uint16_t)(p2 >> 16)) + bf2f((uint16_t)(p3 >> 16))
            + bf2f((uint16_t)(p4 >> 16)) + bf2f((uint16_t)(p5 >> 16)) + bf2f((uint16_t)(p6 >> 16)) + bf2f((uint16_t)(p7 >> 16));
      }
      for (; e < dgc; e++) {
        uint32_t p = *(const uint32_t*)(hsrc + (size_t)sl[e] * DIM + lane * 2);
        a0 += bf2f((uint16_t)p);
        a1 += bf2f((uint16_t)(p >> 16));
      }
      float inv = 1.f / fmaxf((float)dg, 1.f);
      uint32_t o = (uint32_t)f2bf(a0 * inv) | ((uint32_t)f2bf(a1 * inv) << 16);
      *(uint32_t*)&hn[(w * 4 + rr) * HNP + lane * 2] = o;
    }
    __syncthreads();

    // ---- GEMM phase ----
    f32x4 acc[2];
#pragma unroll
    for (int j = 0; j < 2; j++) acc[j] = (f32x4){0.f, 0.f, 0.f, 0.f};

#pragma unroll
    for (int kc = 0; kc < 4; kc++) {
      bf16x8 aS = *(const bf16x8*)(hself + (size_t)(m0 + m16) * DIM + kc * 32 + q * 8);
      bf16x8 aN = *(const bf16x8*)&hn[m16 * HNP + kc * 32 + q * 8];
#pragma unroll
      for (int j = 0; j < 2; j++) {
        int nt = w * 2 + j;
        bf16x8 ws = *(const bf16x8*)&wS[((kc * 8 + nt) * 64 + lane) * 8];
        bf16x8 wn = *(const bf16x8*)&wN[((kc * 8 + nt) * 64 + lane) * 8];
        acc[j] = __builtin_amdgcn_mfma_f32_16x16x32_bf16(aS, ws, acc[j], 0, 0, 0);
        acc[j] = __builtin_amdgcn_mfma_f32_16x16x32_bf16(aN, wn, acc[j], 0, 0, 0);
      }
    }

#pragma unroll
    for (int j = 0; j < 2; j++)
#pragma unroll
      for (int r = 0; r < 4; r++) {
        float v = acc[j][r] + bv[j];
        if (ACT) v = fmaxf(v, 0.f);
        size_t o = (size_t)(m0 + q * 4 + r) * DIM + (w * 2 + j) * 16 + m16;
        if (OUT_BF16) ((uint16_t*)outp)[o] = f2bf(v);
        else          ((float*)outp)[o] = v;
      }
    __syncthreads();   // hn consumed before next group's gather overwrites
  }
}

// ---------------------------------------------------------------------------
// Workspace layout (bytes), total ~79.6 MB (ws_size ~409.6 MB):
//   h      @ 0           200000*128 bf16 = 51,200,000
//   h1     @ 51,200,000   50000*128 bf16 = 12,800,000
//   cnt0   @ 64,000,000   50000 int      =    200,000
//   cnt1   @ 64,200,000   10000 int      =     40,000
//   eslot0 @ 64,240,000   50000*64 int   = 12,800,000
//   eslot1 @ 77,040,000   10000*64 int   =  2,560,000
// ---------------------------------------------------------------------------
extern "C" void kernel_launch(void* const* d_in, const int* in_sizes, int n_in,
                              void* d_out, int out_size, void* d_ws, size_t ws_size,
                              hipStream_t stream) {
  const float* feat   = (const float*)d_in[0];
  const int* src0     = (const int*)d_in[1];
  const int* dst0     = (const int*)d_in[2];
  const int* src1     = (const int*)d_in[3];
  const int* dst1     = (const int*)d_in[4];
  const float* W_init = (const float*)d_in[5];
  const float* b_init = (const float*)d_in[6];
  const float* W_self = (const float*)d_in[7];
  const float* b_self = (const float*)d_in[8];
  const float* W_neigh= (const float*)d_in[9];
  const float* b_neigh= (const float*)d_in[10];

  char* ws = (char*)d_ws;
  uint16_t* h     = (uint16_t*)(ws + 0);
  uint16_t* h1    = (uint16_t*)(ws + 51200000);
  int*      cnt0  = (int*)(ws + 64000000);
  int*      cnt1  = (int*)(ws + 64200000);
  int*      eslot0= (int*)(ws + 64240000);
  int*      eslot1= (int*)(ws + 77040000);

  hipMemsetAsync(cnt0, 0, 240000, stream);   // cnt0 + cnt1 contiguous
  place_kernel<<<1024, 256, 0, stream>>>(src0, dst0, src1, dst1,
                                         cnt0, cnt1, eslot0, eslot1);
  fc_init_kernel<<<512, 256, 0, stream>>>(feat, W_init, b_init, h);

  sage_fused_kernel<true, true><<<512, 256, 0, stream>>>(
      eslot0, cnt0, h, h, W_self, W_neigh, b_self, b_neigh, h1, N_DST0);
  sage_fused_kernel<false, false><<<256, 256, 0, stream>>>(
      eslot1, cnt1, h1, h1, W_self, W_neigh, b_self, b_neigh, d_out, N_DST1);
}

// Round 6
// 309.060 us; speedup vs baseline: 1.3529x; 1.3529x over previous
//
#include <hip/hip_runtime.h>
#include <stdint.h>
#include <stddef.h>

// GraphSAGE-mean 2-layer pipeline on MI355X — round 6.
//   h   = relu(feat @ W_init + b_init)                      [200000,128] bf16 (ws)
//   l0: hn = segment_mean(h[src0], dst0); h1 = relu(h[:50000]@Ws + hn@Wn + b)  bf16
//   l1: hn = segment_mean(h1[src1], dst1); out = h1[:10000]@Ws + hn@Wn + b    f32
//
// R6 vs R5: fusion REVERTED (R5's fused gather had 2048 waves x 392 serial
// dst-drains = 350k cyc = the 135 us; wave-per-dst agg overlaps all drains).
// Law learned R3/R5: throughput of drain-refill phases comes from WAVE COUNT,
// not per-wave loop structure. So every latency-bound kernel is now one-shot:
// one work item per wave, one drain, exit.
//  - fc_init: 12500 one-shot waves (one 16-row strip each), burst loads
//  - sage:    one strip per wave one-shot (782/157 blocks), W frags in LDS
//  - agg:     wave-per-dst one-shot (R4 structure)
//  - prep kernel reinstated (per-block W-frag rebuild would cost 100+ MB L3)

#define DIM 128
constexpr int N_SRC0 = 200000;
constexpr int N_DST0 = 50000;
constexpr int N_DST1 = 10000;
constexpr int E0 = 800000;
constexpr int E1 = 160000;
constexpr int MAXDEG = 64;   // Poisson(16): max deg over 50k bins ~45 — safe

typedef __attribute__((ext_vector_type(8))) short bf16x8;   // 8 bf16 = 4 VGPRs
typedef __attribute__((ext_vector_type(4))) float f32x4;    // MFMA C/D

__device__ __forceinline__ uint16_t f2bf(float f) {
  union { float f; uint32_t u; } v; v.f = f;
  return (uint16_t)((v.u + 0x7FFFu + ((v.u >> 16) & 1u)) >> 16);  // RNE
}
__device__ __forceinline__ float bf2f(uint16_t h) {
  union { uint32_t u; float f; } v; v.u = ((uint32_t)h) << 16;
  return v.f;
}

// ---------------------------------------------------------------------------
// prep: reformat 3 weight matrices (f32) into MFMA-fragment-order bf16 planes,
// and zero the degree counters.
// Wf[m][((kc*8+nt)*64+lane)*8+j] = bf16(W_m[kc*32+(lane>>4)*8+j][nt*16+(lane&15)])
// ---------------------------------------------------------------------------
__global__ __launch_bounds__(512) void prep_w_kernel(
    const float* __restrict__ W0, const float* __restrict__ W1,
    const float* __restrict__ W2, uint16_t* __restrict__ Wf,
    int* __restrict__ cnt, int ncnt) {
  int gid = blockIdx.x * 512 + threadIdx.x;
  if (gid < 3 * 16384) {
    int m = gid >> 14, idx = gid & 16383;
    const float* W = m == 0 ? W0 : (m == 1 ? W1 : W2);
    int j = idx & 7, lane = (idx >> 3) & 63, nt = (idx >> 9) & 7, kc = idx >> 12;
    int k = kc * 32 + (lane >> 4) * 8 + j;
    int n = nt * 16 + (lane & 15);
    Wf[gid] = f2bf(W[k * DIM + n]);
  }
  int z = gid - 3 * 16384;
  if (z >= 0 && z < ncnt) cnt[z] = 0;
}

// ---------------------------------------------------------------------------
// place: dst-partitioned slot-scatter (partition = blockIdx&7, XCD heuristic).
// Each partition scans all edges (int4, L3-absorbed) but writes only its own
// 1/8 dst slice -> slot lines fill in one XCD's L2 before eviction.
// ---------------------------------------------------------------------------
__global__ __launch_bounds__(256) void place_kernel(
    const int* __restrict__ src0, const int* __restrict__ dst0,
    const int* __restrict__ src1, const int* __restrict__ dst1,
    int* __restrict__ cnt0, int* __restrict__ cnt1,
    int* __restrict__ eslot0, int* __restrict__ eslot1) {
  int part = blockIdx.x & 7;
  int bpp  = gridDim.x >> 3;
  int bidx = blockIdx.x >> 3;
  const int4* s04 = (const int4*)src0;
  const int4* d04 = (const int4*)dst0;
  const int4* s14 = (const int4*)src1;
  const int4* d14 = (const int4*)dst1;

  int lo = part * (N_DST0 / 8), hi = lo + (N_DST0 / 8);
  for (int i = bidx * 256 + threadIdx.x; i < E0 / 4; i += bpp * 256) {
    int4 d = d04[i]; int4 s = s04[i];
    if (d.x >= lo && d.x < hi) { int p = atomicAdd(&cnt0[d.x], 1); if (p < MAXDEG) eslot0[(size_t)d.x * MAXDEG + p] = s.x; }
    if (d.y >= lo && d.y < hi) { int p = atomicAdd(&cnt0[d.y], 1); if (p < MAXDEG) eslot0[(size_t)d.y * MAXDEG + p] = s.y; }
    if (d.z >= lo && d.z < hi) { int p = atomicAdd(&cnt0[d.z], 1); if (p < MAXDEG) eslot0[(size_t)d.z * MAXDEG + p] = s.z; }
    if (d.w >= lo && d.w < hi) { int p = atomicAdd(&cnt0[d.w], 1); if (p < MAXDEG) eslot0[(size_t)d.w * MAXDEG + p] = s.w; }
  }
  int lo1 = part * (N_DST1 / 8), hi1 = lo1 + (N_DST1 / 8);
  for (int i = bidx * 256 + threadIdx.x; i < E1 / 4; i += bpp * 256) {
    int4 d = d14[i]; int4 s = s14[i];
    if (d.x >= lo1 && d.x < hi1) { int p = atomicAdd(&cnt1[d.x], 1); if (p < MAXDEG) eslot1[(size_t)d.x * MAXDEG + p] = s.x; }
    if (d.y >= lo1 && d.y < hi1) { int p = atomicAdd(&cnt1[d.y], 1); if (p < MAXDEG) eslot1[(size_t)d.y * MAXDEG + p] = s.y; }
    if (d.z >= lo1 && d.z < hi1) { int p = atomicAdd(&cnt1[d.z], 1); if (p < MAXDEG) eslot1[(size_t)d.z * MAXDEG + p] = s.z; }
    if (d.w >= lo1 && d.w < hi1) { int p = atomicAdd(&cnt1[d.w], 1); if (p < MAXDEG) eslot1[(size_t)d.w * MAXDEG + p] = s.w; }
  }
}

// ---------------------------------------------------------------------------
// fc_init: h = relu(feat @ W + b). ONE strip (16 rows) per wave, one-shot.
// Burst all 8 A-loads, single drain, 32 MFMA, store, exit. W frags in LDS.
// ---------------------------------------------------------------------------
__global__ __launch_bounds__(256) void fc_init_kernel(
    const float* __restrict__ feat, const uint16_t* __restrict__ Wf,
    const float* __restrict__ bias, uint16_t* __restrict__ hout) {
  __shared__ uint16_t wl[16384];                  // 32 KB W fragments
  {
    const uint4* g = (const uint4*)Wf;
    uint4* s = (uint4*)wl;
    for (int i = threadIdx.x; i < 2048; i += 256) s[i] = g[i];
  }
  __syncthreads();

  const int lane = threadIdx.x & 63;
  const int q = lane >> 4, m16 = lane & 15;
  const int s = blockIdx.x * 4 + (threadIdx.x >> 6);   // strip id, one per wave
  if (s >= N_SRC0 / 16) return;

  // burst: all 8 independent 16B loads issued before any use
  const float* ap = feat + (size_t)(s * 16 + m16) * DIM + q * 8;
  float4 X[8];
#pragma unroll
  for (int kc = 0; kc < 4; kc++) {
    X[2 * kc]     = *(const float4*)(ap + kc * 32);
    X[2 * kc + 1] = *(const float4*)(ap + kc * 32 + 4);
  }

  float bv[8];
#pragma unroll
  for (int nt = 0; nt < 8; nt++) bv[nt] = bias[nt * 16 + m16];

  f32x4 acc[8];
#pragma unroll
  for (int nt = 0; nt < 8; nt++) acc[nt] = (f32x4){0.f, 0.f, 0.f, 0.f};

#pragma unroll
  for (int kc = 0; kc < 4; kc++) {
    float xs[8] = {X[2 * kc].x, X[2 * kc].y, X[2 * kc].z, X[2 * kc].w,
                   X[2 * kc + 1].x, X[2 * kc + 1].y, X[2 * kc + 1].z, X[2 * kc + 1].w};
    bf16x8 a;
#pragma unroll
    for (int j = 0; j < 8; j++) a[j] = (short)f2bf(xs[j]);
#pragma unroll
    for (int nt = 0; nt < 8; nt++) {
      bf16x8 w = *(const bf16x8*)&wl[((kc * 8 + nt) * 64 + lane) * 8];
      acc[nt] = __builtin_amdgcn_mfma_f32_16x16x32_bf16(a, w, acc[nt], 0, 0, 0);
    }
  }

  int m0 = s * 16;
#pragma unroll
  for (int nt = 0; nt < 8; nt++)
#pragma unroll
    for (int r = 0; r < 4; r++) {
      float v = fmaxf(acc[nt][r] + bv[nt], 0.f);
      hout[(size_t)(m0 + q * 4 + r) * DIM + nt * 16 + m16] = f2bf(v);
    }
}

// ---------------------------------------------------------------------------
// aggregate: wave per dst, one-shot (50k/10k waves — all gather drains overlap
// across waves). Lane owns 2 feature cols; mean written as bf16.
// ---------------------------------------------------------------------------
__global__ __launch_bounds__(256) void agg_kernel(
    const int* __restrict__ eslot, const int* __restrict__ deg,
    const uint16_t* __restrict__ hsrc, uint16_t* __restrict__ hout, int n_dst) {
  int d = (blockIdx.x * 256 + threadIdx.x) >> 6;
  int lane = threadIdx.x & 63;
  if (d >= n_dst) return;
  const int* sl = eslot + (size_t)d * MAXDEG;
  int dg = deg[d];
  int dgc = dg < MAXDEG ? dg : MAXDEG;
  float a0 = 0.f, a1 = 0.f;
  int e = 0;
  for (; e + 4 <= dgc; e += 4) {
    int s0 = sl[e], s1 = sl[e + 1], s2 = sl[e + 2], s3 = sl[e + 3];
    uint32_t p0 = *(const uint32_t*)(hsrc + (size_t)s0 * DIM + lane * 2);
    uint32_t p1 = *(const uint32_t*)(hsrc + (size_t)s1 * DIM + lane * 2);
    uint32_t p2 = *(const uint32_t*)(hsrc + (size_t)s2 * DIM + lane * 2);
    uint32_t p3 = *(const uint32_t*)(hsrc + (size_t)s3 * DIM + lane * 2);
    a0 += bf2f((uint16_t)p0) + bf2f((uint16_t)p1) + bf2f((uint16_t)p2) + bf2f((uint16_t)p3);
    a1 += bf2f((uint16_t)(p0 >> 16)) + bf2f((uint16_t)(p1 >> 16)) +
          bf2f((uint16_t)(p2 >> 16)) + bf2f((uint16_t)(p3 >> 16));
  }
  for (; e < dgc; e++) {
    uint32_t p = *(const uint32_t*)(hsrc + (size_t)sl[e] * DIM + lane * 2);
    a0 += bf2f((uint16_t)p);
    a1 += bf2f((uint16_t)(p >> 16));
  }
  float inv = 1.f / fmaxf((float)dg, 1.f);
  uint32_t o = (uint32_t)f2bf(a0 * inv) | ((uint32_t)f2bf(a1 * inv) << 16);
  *(uint32_t*)(hout + (size_t)d * DIM + lane * 2) = o;
}

// ---------------------------------------------------------------------------
// sage: out = act(hself@Ws + hneigh@Wn + bS + bN). ONE strip per wave,
// one-shot: burst 8 b128 loads, drain once, 64 MFMA, store, exit.
// Both W planes in LDS (64 KB).
// ---------------------------------------------------------------------------
template <bool ACT, bool OUT_BF16>
__global__ __launch_bounds__(256) void sage_kernel(
    const uint16_t* __restrict__ hself, const uint16_t* __restrict__ hneigh,
    const uint16_t* __restrict__ WfS, const uint16_t* __restrict__ WfN,
    const float* __restrict__ bS, const float* __restrict__ bN,
    void* __restrict__ outp, int n_dst) {
  __shared__ uint16_t wS[16384];
  __shared__ uint16_t wN[16384];
  {
    const uint4* gS = (const uint4*)WfS;
    const uint4* gN = (const uint4*)WfN;
    uint4* sS = (uint4*)wS;
    uint4* sN = (uint4*)wN;
    for (int i = threadIdx.x; i < 2048; i += 256) { sS[i] = gS[i]; sN[i] = gN[i]; }
  }
  __syncthreads();

  const int lane = threadIdx.x & 63;
  const int q = lane >> 4, m16 = lane & 15;
  const int s = blockIdx.x * 4 + (threadIdx.x >> 6);
  if (s >= n_dst / 16) return;

  size_t ro = (size_t)(s * 16 + m16) * DIM + q * 8;
  bf16x8 XS[4], XN[4];
#pragma unroll
  for (int kc = 0; kc < 4; kc++) {
    XS[kc] = *(const bf16x8*)(hself + ro + kc * 32);
    XN[kc] = *(const bf16x8*)(hneigh + ro + kc * 32);
  }

  float bv[8];
#pragma unroll
  for (int nt = 0; nt < 8; nt++)
    bv[nt] = bS[nt * 16 + m16] + bN[nt * 16 + m16];

  f32x4 acc[8];
#pragma unroll
  for (int nt = 0; nt < 8; nt++) acc[nt] = (f32x4){0.f, 0.f, 0.f, 0.f};

#pragma unroll
  for (int kc = 0; kc < 4; kc++) {
#pragma unroll
    for (int nt = 0; nt < 8; nt++) {
      size_t fo = (size_t)((kc * 8 + nt) * 64 + lane) * 8;
      bf16x8 ws = *(const bf16x8*)&wS[fo];
      bf16x8 wn = *(const bf16x8*)&wN[fo];
      acc[nt] = __builtin_amdgcn_mfma_f32_16x16x32_bf16(XS[kc], ws, acc[nt], 0, 0, 0);
      acc[nt] = __builtin_amdgcn_mfma_f32_16x16x32_bf16(XN[kc], wn, acc[nt], 0, 0, 0);
    }
  }

  int m0 = s * 16;
#pragma unroll
  for (int nt = 0; nt < 8; nt++)
#pragma unroll
    for (int r = 0; r < 4; r++) {
      float v = acc[nt][r] + bv[nt];
      if (ACT) v = fmaxf(v, 0.f);
      size_t o = (size_t)(m0 + q * 4 + r) * DIM + nt * 16 + m16;
      if (OUT_BF16) ((uint16_t*)outp)[o] = f2bf(v);
      else          ((float*)outp)[o] = v;
    }
}

// ---------------------------------------------------------------------------
// Workspace layout (bytes), total ~92.7 MB (ws_size ~409.6 MB):
//   h      @ 0           200000*128 bf16 = 51,200,000
//   h1     @ 51,200,000   50000*128 bf16 = 12,800,000
//   cnt0   @ 64,000,000   50000 int      =    200,000
//   cnt1   @ 64,200,000   10000 int      =     40,000
//   eslot0 @ 64,240,000   50000*64 int   = 12,800,000
//   eslot1 @ 77,040,000   10000*64 int   =  2,560,000
//   hn     @ 79,600,000   50000*128 bf16 = 12,800,000
//   Wf     @ 92,400,000   3*16384 bf16   =     98,304
// ---------------------------------------------------------------------------
extern "C" void kernel_launch(void* const* d_in, const int* in_sizes, int n_in,
                              void* d_out, int out_size, void* d_ws, size_t ws_size,
                              hipStream_t stream) {
  const float* feat   = (const float*)d_in[0];
  const int* src0     = (const int*)d_in[1];
  const int* dst0     = (const int*)d_in[2];
  const int* src1     = (const int*)d_in[3];
  const int* dst1     = (const int*)d_in[4];
  const float* W_init = (const float*)d_in[5];
  const float* b_init = (const float*)d_in[6];
  const float* W_self = (const float*)d_in[7];
  const float* b_self = (const float*)d_in[8];
  const float* W_neigh= (const float*)d_in[9];
  const float* b_neigh= (const float*)d_in[10];

  char* ws = (char*)d_ws;
  uint16_t* h     = (uint16_t*)(ws + 0);
  uint16_t* h1    = (uint16_t*)(ws + 51200000);
  int*      cnt0  = (int*)(ws + 64000000);
  int*      cnt1  = (int*)(ws + 64200000);
  int*      eslot0= (int*)(ws + 64240000);
  int*      eslot1= (int*)(ws + 77040000);
  uint16_t* hn    = (uint16_t*)(ws + 79600000);
  uint16_t* WfI   = (uint16_t*)(ws + 92400000);
  uint16_t* WfS   = WfI + 16384;
  uint16_t* WfN   = WfS + 16384;

  prep_w_kernel<<<214, 512, 0, stream>>>(W_init, W_self, W_neigh, WfI, cnt0, 60000);
  place_kernel<<<1024, 256, 0, stream>>>(src0, dst0, src1, dst1,
                                         cnt0, cnt1, eslot0, eslot1);

  fc_init_kernel<<<3125, 256, 0, stream>>>(feat, WfI, b_init, h);

  // ---- layer 0 ----
  agg_kernel<<<12500, 256, 0, stream>>>(eslot0, cnt0, h, hn, N_DST0);
  sage_kernel<true, true><<<782, 256, 0, stream>>>(h, hn, WfS, WfN,
                                                   b_self, b_neigh, h1, N_DST0);

  // ---- layer 1 ----
  agg_kernel<<<2500, 256, 0, stream>>>(eslot1, cnt1, h1, hn, N_DST1);
  sage_kernel<false, false><<<157, 256, 0, stream>>>(h1, hn, WfS, WfN,
                                                     b_self, b_neigh, d_out, N_DST1);
}